// Round 9
// baseline (171.463 us; speedup 1.0000x reference)
//
#include <hip/hip_runtime.h>
#include <hip/hip_bf16.h>
#include <math.h>

#define DDIM 7168
#define NEXP 256
#define NGRP 8
#define TOPKG 4
#define TOPK 8
#define ROUTE_SCALE 2.5f

#define BM 128
#define BN 256
#define BK 32
#define KSPLIT 4
#define KPER (DDIM / KSPLIT)        // 1792
#define NSTEP (KPER / BK)           // 56
#define NKTILE (DDIM / BK)          // 224
#define BT_ELEMS (NEXP * BK * 2)    // 16384 shorts = 32 KB per k-step tile

typedef __attribute__((ext_vector_type(8))) short bf16x8;
typedef __attribute__((ext_vector_type(4))) float f32x4;
typedef unsigned int u32;
typedef unsigned short ushort_t;

static __device__ __forceinline__ ushort_t bf16_rne(float f) {
    u32 b = __float_as_uint(f);
    u32 r = (b + 0x7fffu + ((b >> 16) & 1u)) >> 16;
    return (ushort_t)r;
}
static __device__ __forceinline__ float bf16_to_f32(ushort_t h) {
    return __uint_as_float(((u32)h) << 16);
}
// hi = bf16(f) via HW cvt; lo = bf16(f - hi)
static __device__ __forceinline__ void split_elem(float f, short& h, short& l) {
    union { __hip_bfloat16 b; short s; } cv;
    cv.b = __float2bfloat16(f);
    h = cv.s;
    float hf = __uint_as_float(((u32)(ushort_t)cv.s) << 16);
    cv.b = __float2bfloat16(f - hf);
    l = cv.s;
}

// ---------------------------------------------------------------------------
// Kernel 0: split w into hi/lo bf16, fragment-linear per BK=32 k-tile.
// Tile (32 KB): [split(2)][fn(16)][lane(64)][8 bf16]  — R3-proven layout.
// element = split of W[fn*16 + (lane&15)][kt*32 + (lane>>4)*8 + j]
// ---------------------------------------------------------------------------
__global__ __launch_bounds__(256) void wsplit_kernel(const float* __restrict__ w,
                                                     short* __restrict__ wsp)
{
    const int kt = blockIdx.x;      // 0..223
    const int e  = threadIdx.x;     // expert 0..255
    const float* wp = w + (size_t)e * DDIM + (size_t)kt * BK;
    short* tb = wsp + (size_t)kt * BT_ELEMS;
    const int fn = e >> 4, er = e & 15;
    #pragma unroll
    for (int jg = 0; jg < 4; jg++) {
        float f[8];
        *(float4*)&f[0] = *(const float4*)(wp + jg * 8);
        *(float4*)&f[4] = *(const float4*)(wp + jg * 8 + 4);
        ushort_t h[8], l[8];
        #pragma unroll
        for (int j = 0; j < 8; j++) {
            h[j] = bf16_rne(f[j]);
            l[j] = bf16_rne(f[j] - bf16_to_f32(h[j]));
        }
        const int lane = jg * 16 + er;
        *(uint4*)(tb + ((size_t)(0 * 16 + fn) * 64 + lane) * 8) = *(uint4*)h;
        *(uint4*)(tb + ((size_t)(1 * 16 + fn) * 64 + lane) * 8) = *(uint4*)l;
    }
}

// ---------------------------------------------------------------------------
// Kernel 1: split-precision bf16 MFMA GEMM — fully-decoupled 2-deep pipeline.
// grid = 64 mt x 4 ksp = 256 blocks (1/CU); 512 thr = 8 waves (2 wm x 4 wn),
// wave tile 64x64. BN=256: each x row enters exactly ONE CU (R8's nh split
// doubled L3->CU ingress). B: 3-buffer LDS, STAGE_B(st+2) each step (2-step
// landing window). A: 2-deep register ping-pong, LOAD_A(st+2) issued right
// after convert(st) frees the buffer (~1.8 steps of latency cover) — R8's
// 1-step A chain carried a full loaded-HBM latency per step.
// Barrier: s_waitcnt vmcnt(12) [worst-case ops younger than B(st) under any
// intra-step reorder: A(st) 8 + A(st+1)/B(st+1) up to 12, min bound 12]
// + lgkmcnt(0) + raw s_barrier. Never vmcnt(0) in the main loop (T4).
// ---------------------------------------------------------------------------
__global__ __launch_bounds__(512, 2) void gemm_split_kernel(
    const float* __restrict__ x, const short* __restrict__ wsp,
    float* __restrict__ part, int Btok)
{
    __shared__ short Blds[3][BT_ELEMS];   // 3 x 32 KB = 96 KB

    const int bid  = blockIdx.x;
    const int mt   = bid >> 2;            // 0..63
    const int ksp  = bid & 3;             // natural XCD partition of wsp
    const int m0   = mt * BM;
    const int kbase = ksp * KPER;
    const int t    = threadIdx.x;
    const int wid  = t >> 6, lane = t & 63;
    const int wm   = wid >> 2, wn = wid & 3;
    const int lr   = lane & 15, lg = lane >> 4;

    const short* wt0 = wsp + (size_t)(ksp * NSTEP) * BT_ELEMS;
    // A: rows m0 + wm*64 + fm*16 + lr ; k = kbase + st*32 + lg*8
    const float* abase = x + (size_t)(m0 + wm * 64 + lr) * DDIM + kbase + lg * 8;

#define STAGE_B(stp, dst) do {                                                             \
        const short* gt_ = wt0 + (size_t)(stp) * BT_ELEMS;                                 \
        _Pragma("unroll")                                                                  \
        for (int i_ = 0; i_ < 4; i_++) {                                                   \
            const int off_ = wid * 4096 + i_ * 1024;                                       \
            __builtin_amdgcn_global_load_lds(                                              \
                (const __attribute__((address_space(1))) u32*)((const char*)gt_ + off_ + lane * 16), \
                (__attribute__((address_space(3))) u32*)((char*)(dst) + off_),             \
                16, 0, 0);                                                                 \
        } } while (0)

#define LOAD_A(stp, ABUF) do {                                                             \
        _Pragma("unroll")                                                                  \
        for (int fm_ = 0; fm_ < 4; fm_++) {                                                \
            const float* ap_ = abase + (size_t)fm_ * 16 * DDIM + (size_t)(stp) * BK;       \
            *(float4*)&ABUF[fm_][0] = *(const float4*)(ap_);                               \
            *(float4*)&ABUF[fm_][4] = *(const float4*)(ap_ + 4);                           \
        } } while (0)

    f32x4 acc[4][4];
    #pragma unroll
    for (int i = 0; i < 4; i++)
        #pragma unroll
        for (int j = 0; j < 4; j++) acc[i][j] = (f32x4){0.f, 0.f, 0.f, 0.f};

    float aA[4][8], aB[4][8];

    // ---- prologue: B(0), A(0), B(1), A(1) in flight (order sets vmcnt math) ----
    STAGE_B(0, &Blds[0][0]);
    LOAD_A(0, aA);
    STAGE_B(1, &Blds[1][0]);
    LOAD_A(1, aB);

    short* bp_r = &Blds[0][0];   // holds B(st)
    short* bp_1 = &Blds[1][0];   // holds B(st+1)
    short* bp_2 = &Blds[2][0];   // destination for B(st+2)

#define STEP_BODY(st, ABUF) do {                                                           \
        if ((st) < NSTEP - 1) { asm volatile("s_waitcnt vmcnt(12)" ::: "memory"); }        \
        else                  { asm volatile("s_waitcnt vmcnt(0)"  ::: "memory"); }        \
        asm volatile("s_waitcnt lgkmcnt(0)" ::: "memory");                                 \
        __builtin_amdgcn_s_barrier();                                                      \
        /* issue B(st+2) DMA into the buffer read at step st-1 (WAR: done) */              \
        if ((st) + 2 < NSTEP) STAGE_B((st) + 2, bp_2);                                     \
        /* convert A(st) -> hi/lo fragments (operands landed ~2 steps ago) */              \
        bf16x8 ah[4], al[4];                                                               \
        _Pragma("unroll")                                                                  \
        for (int fm = 0; fm < 4; fm++) {                                                   \
            union { bf16x8 v; short s[8]; } H_, L_;                                        \
            _Pragma("unroll")                                                              \
            for (int j = 0; j < 8; j++)                                                    \
                split_elem(ABUF[fm][j], H_.s[j], L_.s[j]);                                 \
            ah[fm] = H_.v;                                                                 \
            al[fm] = L_.v;                                                                 \
        }                                                                                  \
        /* reuse freed buffer: issue A(st+2) (lands over ~1.8 steps) */                    \
        if ((st) + 2 < NSTEP) LOAD_A((st) + 2, ABUF);                                      \
        /* MFMA: C += Ah*Bh + Ah*Bl + Al*Bh  (48/wave/step) */                             \
        __builtin_amdgcn_s_setprio(1);                                                     \
        _Pragma("unroll")                                                                  \
        for (int fn = 0; fn < 4; fn++) {                                                   \
            const bf16x8 bh = *(const bf16x8*)&bp_r[((size_t)(0 * 16 + wn * 4 + fn) * 64 + lane) * 8]; \
            const bf16x8 bl = *(const bf16x8*)&bp_r[((size_t)(1 * 16 + wn * 4 + fn) * 64 + lane) * 8]; \
            _Pragma("unroll")                                                              \
            for (int fm = 0; fm < 4; fm++) {                                               \
                acc[fm][fn] = __builtin_amdgcn_mfma_f32_16x16x32_bf16(ah[fm], bh, acc[fm][fn], 0, 0, 0); \
                acc[fm][fn] = __builtin_amdgcn_mfma_f32_16x16x32_bf16(ah[fm], bl, acc[fm][fn], 0, 0, 0); \
                acc[fm][fn] = __builtin_amdgcn_mfma_f32_16x16x32_bf16(al[fm], bh, acc[fm][fn], 0, 0, 0); \
            }                                                                              \
        }                                                                                  \
        __builtin_amdgcn_s_setprio(0);                                                     \
        { short* tmp_ = bp_r; bp_r = bp_1; bp_1 = bp_2; bp_2 = tmp_; }                     \
    } while (0)

    for (int st2 = 0; st2 < NSTEP; st2 += 2) {
        STEP_BODY(st2,     aA);
        STEP_BODY(st2 + 1, aB);
    }
#undef STEP_BODY
#undef STAGE_B
#undef LOAD_A

    // ---- epilogue: fp32 partials (C/D map: col=lane&15, row=(lane>>4)*4+reg) ----
    float* pp = part + (size_t)ksp * (size_t)Btok * NEXP;
    #pragma unroll
    for (int fm = 0; fm < 4; fm++) {
        const int row0 = m0 + wm * 64 + fm * 16 + lg * 4;
        #pragma unroll
        for (int fn = 0; fn < 4; fn++) {
            const int col = wn * 64 + fn * 16 + lr;
            #pragma unroll
            for (int rr = 0; rr < 4; rr++)
                pp[(size_t)(row0 + rr) * NEXP + col] = acc[fm][fn][rr];
        }
    }
}

// ---------------------------------------------------------------------------
// Kernel 2: reduce split-K partials + sigmoid + full gating, one wave per row.
// (unchanged — proven)
// ---------------------------------------------------------------------------
__global__ __launch_bounds__(256) void gate_kernel(
    const float* __restrict__ part, const float* __restrict__ bias,
    float* __restrict__ out_w, float* __restrict__ out_i, int B)
{
    const int lane = threadIdx.x & 63;
    const int wid  = threadIdx.x >> 6;
    const int row  = blockIdx.x * 4 + wid;
    if (row >= B) return;

    const size_t plane = (size_t)B * NEXP;
    const float* pr = part + (size_t)row * NEXP + lane * 4;
    float4 v0 = *(const float4*)(pr);
    float4 v1 = *(const float4*)(pr + plane);
    float4 v2 = *(const float4*)(pr + 2 * plane);
    float4 v3 = *(const float4*)(pr + 3 * plane);
    float sc[4] = { v0.x + v1.x + v2.x + v3.x,
                    v0.y + v1.y + v2.y + v3.y,
                    v0.z + v1.z + v2.z + v3.z,
                    v0.w + v1.w + v2.w + v3.w };
    float4 bv = *(const float4*)(bias + lane * 4);
    const float bb[4] = { bv.x, bv.y, bv.z, bv.w };

    float so[4], sb[4];
    #pragma unroll
    for (int j = 0; j < 4; j++) {
        so[j] = 1.0f / (1.0f + expf(-sc[j]));
        sb[j] = so[j] + bb[j];
    }

    // ---- group scores: sum of top-2 of sb within each 32-expert group ----
    float m1 = sb[0], m2 = -INFINITY;
    #pragma unroll
    for (int j = 1; j < 4; j++) {
        if (sb[j] > m1)      { m2 = m1; m1 = sb[j]; }
        else if (sb[j] > m2) { m2 = sb[j]; }
    }
    #pragma unroll
    for (int m = 1; m <= 4; m <<= 1) {
        float o1 = __shfl_xor(m1, m);
        float o2 = __shfl_xor(m2, m);
        float hi = fmaxf(m1, o1);
        float lo = fminf(m1, o1);
        m1 = hi;
        m2 = fmaxf(lo, fmaxf(m2, o2));
    }
    float gscore = m1 + m2;
    int g = lane >> 3;

    // ---- top-4 groups (value desc, index asc) ----
    float gs[NGRP];
    #pragma unroll
    for (int gg = 0; gg < NGRP; gg++) gs[gg] = __shfl(gscore, gg * 8);
    int rank = 0;
    #pragma unroll
    for (int gg = 0; gg < NGRP; gg++) {
        if (gg == g) continue;
        if (gs[gg] > gs[g] || (gs[gg] == gs[g] && gg < g)) rank++;
    }
    const bool selg = (rank < TOPKG);
    float mv[4];
    #pragma unroll
    for (int j = 0; j < 4; j++) mv[j] = selg ? sb[j] : -INFINITY;

    // ---- iterative top-8 wave argmax (value desc, index asc) ----
    float wsel[TOPK];
    int   isel[TOPK];
    float wsum = 0.f;
    #pragma unroll
    for (int it = 0; it < TOPK; it++) {
        float v = mv[0]; int jj = 0;
        #pragma unroll
        for (int j = 1; j < 4; j++)
            if (mv[j] > v) { v = mv[j]; jj = j; }
        int gi = (lane << 2) | jj;
        #pragma unroll
        for (int m = 1; m < 64; m <<= 1) {
            float ov = __shfl_xor(v, m);
            int   oi = __shfl_xor(gi, m);
            if (ov > v || (ov == v && oi < gi)) { v = ov; gi = oi; }
        }
        int slot = gi & 3, src = gi >> 2;
        float cand = (slot == 0) ? so[0] : (slot == 1) ? so[1] : (slot == 2) ? so[2] : so[3];
        float sval = __shfl(cand, src);
        wsel[it] = sval; isel[it] = gi; wsum += sval;
        if (lane == src) mv[slot] = -INFINITY;
    }

    if (lane == 0) {
        float scl = ROUTE_SCALE / wsum;
        #pragma unroll
        for (int it = 0; it < TOPK; it++) {
            out_w[(size_t)row * TOPK + it] = wsel[it] * scl;
            out_i[(size_t)row * TOPK + it] = (float)isel[it];
        }
    }
}

extern "C" void kernel_launch(void* const* d_in, const int* in_sizes, int n_in,
                              void* d_out, int out_size, void* d_ws, size_t ws_size,
                              hipStream_t stream)
{
    const float* x    = (const float*)d_in[0];
    const float* w    = (const float*)d_in[1];
    const float* bias = (const float*)d_in[2];
    const int B = in_sizes[0] / DDIM;           // 8192

    // ws layout: [ part: 4 * B * 256 f32 = 32 MB ][ wsp: 224 tiles * 32 KB = 7.34 MB ]
    float* part = (float*)d_ws;
    short* wsp  = (short*)((char*)d_ws + (size_t)KSPLIT * B * NEXP * sizeof(float));

    float* out_w = (float*)d_out;
    float* out_i = out_w + (size_t)B * TOPK;

    hipLaunchKernelGGL(wsplit_kernel, dim3(NKTILE), dim3(256), 0, stream, w, wsp);
    hipLaunchKernelGGL(gemm_split_kernel, dim3((B / BM) * KSPLIT), dim3(512), 0, stream,
                       x, wsp, part, B);
    hipLaunchKernelGGL(gate_kernel, dim3((B + 3) / 4), dim3(256), 0, stream,
                       part, bias, out_w, out_i, B);
}